// Round 5
// baseline (434.199 us; speedup 1.0000x reference)
//
#include <hip/hip_runtime.h>
#include <hip/hip_bf16.h>

#define DI __device__ __forceinline__

typedef unsigned int u32;
typedef unsigned short u16;
typedef __attribute__((ext_vector_type(8))) short short8;
typedef __attribute__((ext_vector_type(4))) float f32x4;

DI u16 f2bf(float f) {
  union { float f; u32 x; } t; t.f = f;
  u32 x = t.x;
  u32 r = (x + 0x7fffu + ((x >> 16) & 1u)) >> 16;   // RNE
  return (u16)r;
}

typedef __attribute__((address_space(3))) u32 lds_u32;
typedef const __attribute__((address_space(1))) u32 gbl_u32;
DI void gl_lds16(const u16* g, u16* l) {
  __builtin_amdgcn_global_load_lds((gbl_u32*)(const void*)g, (lds_u32*)(void*)l, 16, 0, 0);
}

// ---------------- conv1 via MFMA: x[256,1,28,28] -> hT[b][pix][ic] bf16 ----------------
// per block: one image. im2col [400 pix][96 k] bf16 in LDS (k = ky*9+kx, pad 81..95 = 0),
// w1s [256 oc][96 k]. C[pix][oc] = sum_k im*w1s. Granule XOR-swizzle slot = g ^ ((row>>1)&3).
__global__ __launch_bounds__(256) void conv1_kernel(
    const float* __restrict__ x, const float* __restrict__ w1,
    const float* __restrict__ b1, u16* __restrict__ hT) {
  __shared__ u16 imS[400 * 96];
  __shared__ u16 wsS[256 * 96];
  int b = blockIdx.x, tid = threadIdx.x;
  int lane = tid & 63, wid = tid >> 6;
  const float* xb = x + (size_t)b * 784;
  // build w1s (w1 layout [oc][81])
  for (int t = tid; t < 20736; t += 256) {
    int oc = t / 81, kk = t % 81;
    int g = (kk >> 3) & 3, ph = (kk & ~31) | (((g ^ ((oc >> 1) & 3)) << 3)) | (kk & 7);
    wsS[oc * 96 + ph] = f2bf(w1[t]);
  }
  for (int t = tid; t < 256 * 15; t += 256) {
    int oc = t / 15, kk = 81 + t % 15;
    int g = (kk >> 3) & 3, ph = (kk & ~31) | (((g ^ ((oc >> 1) & 3)) << 3)) | (kk & 7);
    wsS[oc * 96 + ph] = 0;
  }
  // build im2col
  for (int t = tid; t < 32400; t += 256) {
    int pix = t / 81, kk = t % 81;
    int py = pix / 20, px = pix % 20, ky = kk / 9, kx = kk % 9;
    int g = (kk >> 3) & 3, ph = (kk & ~31) | (((g ^ ((pix >> 1) & 3)) << 3)) | (kk & 7);
    imS[pix * 96 + ph] = f2bf(xb[(py + ky) * 28 + px + kx]);
  }
  for (int t = tid; t < 400 * 15; t += 256) {
    int pix = t / 15, kk = 81 + t % 15;
    int g = (kk >> 3) & 3, ph = (kk & ~31) | (((g ^ ((pix >> 1) & 3)) << 3)) | (kk & 7);
    imS[pix * 96 + ph] = 0;
  }
  __syncthreads();
  int l15 = lane & 15, lh = lane >> 4;
  int slot8 = (lh ^ ((l15 >> 1) & 3)) << 3;
  short8 br[4][3];
  float bias[4];
#pragma unroll
  for (int ni = 0; ni < 4; ++ni) {
    int row = wid * 64 + ni * 16 + l15;
    bias[ni] = b1[row];
#pragma unroll
    for (int ksb = 0; ksb < 3; ++ksb)
      br[ni][ksb] = *(const short8*)&wsS[row * 96 + ksb * 32 + slot8];
  }
  for (int mt = 0; mt < 25; ++mt) {
    f32x4 acc[4];
#pragma unroll
    for (int ni = 0; ni < 4; ++ni) acc[ni] = (f32x4){0.f, 0.f, 0.f, 0.f};
    short8 ar[3];
#pragma unroll
    for (int ksb = 0; ksb < 3; ++ksb)
      ar[ksb] = *(const short8*)&imS[(mt * 16 + l15) * 96 + ksb * 32 + slot8];
#pragma unroll
    for (int ksb = 0; ksb < 3; ++ksb)
#pragma unroll
      for (int ni = 0; ni < 4; ++ni)
        acc[ni] = __builtin_amdgcn_mfma_f32_16x16x32_bf16(ar[ksb], br[ni][ksb], acc[ni], 0, 0, 0);
#pragma unroll
    for (int ni = 0; ni < 4; ++ni)
#pragma unroll
      for (int reg = 0; reg < 4; ++reg)
        hT[((size_t)b * 400 + mt * 16 + lh * 4 + reg) * 256 + wid * 64 + ni * 16 + l15] =
            f2bf(acc[ni][reg] + bias[ni]);
  }
}

// ---------------- weight transform: w2[oc][ic*81+tap] -> w2bT[tap][oc][ic] bf16 ----------------
__global__ __launch_bounds__(256) void w2b_kernel(
    const float* __restrict__ w2, u16* __restrict__ w2bT) {
  __shared__ float ws[5184]; // 64 ic * 81 taps
  int oc = blockIdx.x, tid = threadIdx.x;
  for (int ch = 0; ch < 4; ++ch) {
    __syncthreads();
    for (int t = tid; t < 5184; t += 256) ws[t] = w2[(size_t)oc * 20736 + ch * 5184 + t];
    __syncthreads();
    for (int t = tid; t < 5184; t += 256) {
      int tap = t >> 6, icl = t & 63;
      w2bT[((size_t)tap * 256 + oc) * 256 + ch * 64 + icl] = f2bf(ws[icl * 81 + tap]);
    }
  }
}

// ---------------- conv2: 256x256 tile, BK=32, depth-3 pipeline, counted vmcnt ----------------
// C[b][oc] for fixed pixel p; K sliced 7 ways (tap = j*7+ks). 8 waves (2M x 4N).
// writes pp[ks][oc][p][b] fp32 partials
__global__ __launch_bounds__(512, 2) void conv2_mfma_kernel(
    const u16* __restrict__ hT, const u16* __restrict__ w2bT,
    float* __restrict__ pp) {
  __shared__ u16 Ab[4 * 8192]; // 4 bufs x [256 b][32 k]
  __shared__ u16 Bb[4 * 8192]; // 4 bufs x [256 oc][32 k]
  int p = blockIdx.x, ks = blockIdx.y;   // 36 x 7
  int py = p / 6, px = p % 6;
  int tid = threadIdx.x, wid = tid >> 6, lane = tid & 63;
  int ntap = (ks < 4) ? 12 : 11;
  int nch = ntap * 8;   // 96 or 88 chunks of K=32

  // staging: thread t covers (row = t>>2 [+128], granule g = t&3), source pre-swizzled
  int srow = tid >> 2;
  int gsw = ((tid & 3) ^ ((tid >> 3) & 3)) * 8;
  const u16* baseA0 = hT + (size_t)srow * 102400 + gsw;
  const u16* baseA1 = baseA0 + (size_t)128 * 102400;
  const u16* baseB0 = w2bT + (size_t)srow * 256 + gsw;
  const u16* baseB1 = baseB0 + 128 * 256;
  u16* ldsA = &Ab[tid * 8];
  u16* ldsB = &Bb[tid * 8];

#define STAGE(T, BUF) do {                                              \
    int tap_ = ((T) >> 3) * 7 + ks;                                     \
    int icc_ = ((T) & 7) << 5;                                          \
    int pix_ = (2 * py + tap_ / 9) * 20 + (2 * px + tap_ % 9);          \
    int tofsA_ = pix_ * 256 + icc_;                                     \
    size_t tofsB_ = (size_t)tap_ * 65536 + icc_;                        \
    gl_lds16(baseA0 + tofsA_, ldsA + (BUF) * 8192);                     \
    gl_lds16(baseA1 + tofsA_, ldsA + (BUF) * 8192 + 4096);              \
    gl_lds16(baseB0 + tofsB_, ldsB + (BUF) * 8192);                     \
    gl_lds16(baseB1 + tofsB_, ldsB + (BUF) * 8192 + 4096);              \
  } while (0)

  f32x4 acc[8][4];
#pragma unroll
  for (int i = 0; i < 8; ++i)
#pragma unroll
    for (int j = 0; j < 4; ++j) acc[i][j] = (f32x4){0.f, 0.f, 0.f, 0.f};

  int wr = wid >> 2, wc = wid & 3;
  int l15 = lane & 15, lh = lane >> 4;
  int slot8 = (lh ^ ((l15 >> 1) & 3)) << 3;
  int lofsA = wr * 4096 + l15 * 32 + slot8;  // + mi*512
  int lofsB = wc * 2048 + l15 * 32 + slot8;  // + ni*512

  STAGE(0, 0); STAGE(1, 1); STAGE(2, 2);   // 12 loads in flight

  for (int t = 0; t < nch; ++t) {
    if (t + 2 < nch)      asm volatile("s_waitcnt vmcnt(8)" ::: "memory");
    else if (t + 1 < nch) asm volatile("s_waitcnt vmcnt(4)" ::: "memory");
    else                  asm volatile("s_waitcnt vmcnt(0)" ::: "memory");
    __builtin_amdgcn_sched_barrier(0);
    __builtin_amdgcn_s_barrier();
    __builtin_amdgcn_sched_barrier(0);
    if (t + 3 < nch) STAGE(t + 3, (t + 3) & 3);
    const u16* A = &Ab[(t & 3) * 8192];
    const u16* B = &Bb[(t & 3) * 8192];
    short8 ar[8], br[4];
#pragma unroll
    for (int ni = 0; ni < 4; ++ni) br[ni] = *(const short8*)&B[lofsB + ni * 512];
#pragma unroll
    for (int mi = 0; mi < 8; ++mi) ar[mi] = *(const short8*)&A[lofsA + mi * 512];
    __builtin_amdgcn_s_setprio(1);
#pragma unroll
    for (int mi = 0; mi < 8; ++mi)
#pragma unroll
      for (int ni = 0; ni < 4; ++ni)
        acc[mi][ni] = __builtin_amdgcn_mfma_f32_16x16x32_bf16(ar[mi], br[ni], acc[mi][ni], 0, 0, 0);
    __builtin_amdgcn_s_setprio(0);
  }
#undef STAGE

  // epilogue: pp[ks][oc][p][b], float4 over b (4 regs = 4 consecutive b)
  float* ppk = pp + (size_t)ks * 2359296 + (size_t)p * 256;
#pragma unroll
  for (int mi = 0; mi < 8; ++mi) {
    int b = wr * 128 + mi * 16 + lh * 4;
#pragma unroll
    for (int ni = 0; ni < 4; ++ni) {
      int oc = wc * 64 + ni * 16 + l15;
      *(float4*)&ppk[(size_t)oc * 9216 + b] = *(float4*)&acc[mi][ni];
    }
  }
}

// ---------------- split-K reduce + bias: prim2T[flat][b] = sum_ks pp + b2[flat/36] ----------------
__global__ __launch_bounds__(256) void prim_reduce_kernel(
    const float* __restrict__ pp, const float* __restrict__ b2,
    float* __restrict__ prim2T) {
  int e = blockIdx.x * 256 + threadIdx.x;   // float4 index, 589824 total
  int flat = e >> 6;
  float bias = b2[flat / 36];
  const float4* p0 = (const float4*)pp;
  float4 r = p0[e];
#pragma unroll
  for (int ks = 1; ks < 7; ++ks) {
    float4 a = p0[(size_t)ks * 589824 + e];
    r.x += a.x; r.y += a.y; r.z += a.z; r.w += a.w;
  }
  r.x += bias; r.y += bias; r.z += bias; r.w += bias;
  ((float4*)prim2T)[e] = r;
}

// ---------------- softmax over n per class + cb[i][k] = sum_n c*Wb ----------------
__global__ __launch_bounds__(256) void softmax_cb_kernel(
    const float* __restrict__ bij, const float* __restrict__ Wb,
    float* __restrict__ c, float* __restrict__ cb) {
  __shared__ float red[256];
  __shared__ float red2[256][17];
  int i = blockIdx.x, tid = threadIdx.x;
  float m = -1e30f;
  for (int n = tid; n < 1152; n += 256) m = fmaxf(m, bij[i * 1152 + n]);
  red[tid] = m; __syncthreads();
  for (int s = 128; s > 0; s >>= 1) { if (tid < s) red[tid] = fmaxf(red[tid], red[tid + s]); __syncthreads(); }
  m = red[0]; __syncthreads();
  float sum = 0.f;
  for (int n = tid; n < 1152; n += 256) sum += expf(bij[i * 1152 + n] - m);
  red[tid] = sum; __syncthreads();
  for (int s = 128; s > 0; s >>= 1) { if (tid < s) red[tid] += red[tid + s]; __syncthreads(); }
  float inv = 1.0f / red[0];
  float acc[16];
#pragma unroll
  for (int k = 0; k < 16; ++k) acc[k] = 0.f;
  for (int n = tid; n < 1152; n += 256) {
    float cv = expf(bij[i * 1152 + n] - m) * inv;
    c[i * 1152 + n] = cv;
    int mm = i * 1152 + n;
    const float* wb = Wb + (size_t)(mm % 10) * 18432 + (size_t)(mm / 10) * 16;
#pragma unroll
    for (int k = 0; k < 16; ++k) acc[k] += cv * wb[k];
  }
#pragma unroll
  for (int k = 0; k < 16; ++k) red2[tid][k] = acc[k];
  __syncthreads();
  for (int s = 128; s > 0; s >>= 1) {
    if (tid < s) {
#pragma unroll
      for (int k = 0; k < 16; ++k) red2[tid][k] += red2[tid + s][k];
    }
    __syncthreads();
  }
  if (tid < 16) cb[i * 16 + tid] = red2[0][tid];
}

// ---------------- fused CW-build + vgemm: vp[ch][i][b][k] ----------------
__global__ __launch_bounds__(256) void cwvgemm_kernel(
    const float* __restrict__ c, const float* __restrict__ W,
    const float* __restrict__ prim2T, float* __restrict__ vp) {
  __shared__ float cws[1920]; // [15 loc][8 c][16 k]
  int ch = blockIdx.x, i = blockIdx.y, tid = threadIdx.x;
  int loc_min = (i * 1152) / 10;
  int loc_max = ((i + 1) * 1152 - 1) / 10;
  int lc0 = loc_min + ch * 15;
  // build CW slice for this class: cws[ll][cc][k] = sum_{io: (loc*10+io)/1152==i} c * W[io][loc][k*8+cc]
  for (int t = tid; t < 1920; t += 256) {
    int ll = t >> 7, rem = t & 127, k = rem >> 3, cc = rem & 7;
    int loc = lc0 + ll;
    float a = 0.f;
    if (loc <= loc_max) {
      for (int io = 0; io < 10; ++io) {
        int mm = loc * 10 + io;
        if (mm / 1152 == i)
          a += c[i * 1152 + mm % 1152] * W[(size_t)io * 147456 + (size_t)loc * 128 + k * 8 + cc];
      }
    }
    cws[ll * 128 + cc * 16 + k] = a;
  }
  __syncthreads();
  float acc[16];
#pragma unroll
  for (int k = 0; k < 16; ++k) acc[k] = 0.f;
  for (int ll = 0; ll < 15; ++ll) {
    int loc = lc0 + ll;
    if (loc > loc_max) break;
    const float* pr = prim2T + (size_t)loc * 8 * 256 + tid;
    const float* cw = cws + ll * 128;
#pragma unroll
    for (int cc = 0; cc < 8; ++cc) {
      float pvv = pr[cc * 256];
      float4 a0 = *(const float4*)&cw[cc * 16];
      float4 a1 = *(const float4*)&cw[cc * 16 + 4];
      float4 a2 = *(const float4*)&cw[cc * 16 + 8];
      float4 a3 = *(const float4*)&cw[cc * 16 + 12];
      acc[0] += pvv * a0.x; acc[1] += pvv * a0.y; acc[2] += pvv * a0.z; acc[3] += pvv * a0.w;
      acc[4] += pvv * a1.x; acc[5] += pvv * a1.y; acc[6] += pvv * a1.z; acc[7] += pvv * a1.w;
      acc[8] += pvv * a2.x; acc[9] += pvv * a2.y; acc[10] += pvv * a2.z; acc[11] += pvv * a2.w;
      acc[12] += pvv * a3.x; acc[13] += pvv * a3.y; acc[14] += pvv * a3.z; acc[15] += pvv * a3.w;
    }
  }
  float* dst = vp + ((size_t)(ch * 10 + i) * 256 + tid) * 16;
#pragma unroll
  for (int k = 0; k < 16; ++k) dst[k] = acc[k];
}

// ---------------- squash_combine: v = squash(sum_ch vp + cb); sv; out on final ----------------
__global__ __launch_bounds__(256) void squash_combine_kernel(
    const float* __restrict__ vp, const float* __restrict__ cb,
    float* __restrict__ v2, float* __restrict__ sv, float* __restrict__ out, int finalf) {
  __shared__ float red[256];
  __shared__ float red2[256][17];
  int i = blockIdx.x, tid = threadIdx.x;
  float vpre[16];
#pragma unroll
  for (int k = 0; k < 16; ++k) vpre[k] = cb[i * 16 + k];
  for (int ch = 0; ch < 8; ++ch) {
    const float4* src = (const float4*)(vp + ((size_t)(ch * 10 + i) * 256 + tid) * 16);
#pragma unroll
    for (int q = 0; q < 4; ++q) {
      float4 a = src[q];
      vpre[q * 4 + 0] += a.x; vpre[q * 4 + 1] += a.y; vpre[q * 4 + 2] += a.z; vpre[q * 4 + 3] += a.w;
    }
  }
  float ss = 0.f;
#pragma unroll
  for (int k = 0; k < 16; ++k) { ss += vpre[k] * vpre[k]; red2[tid][k] = vpre[k]; }
  red[tid] = ss; __syncthreads();
  for (int s = 128; s > 0; s >>= 1) {
    if (tid < s) {
      red[tid] += red[tid + s];
#pragma unroll
      for (int k = 0; k < 16; ++k) red2[tid][k] += red2[tid + s][k];
    }
    __syncthreads();
  }
  float nrm = sqrtf(red[0]);
  float n2 = nrm * nrm;
  float scale = nrm / (1.f + n2);
  if (tid < 16) sv[i * 16 + tid] = scale * red2[0][tid];
  float* dst = (finalf ? out : v2) + (size_t)i * 4096 + tid * 16;
#pragma unroll
  for (int k = 0; k < 16; ++k) dst[k] = vpre[k] * scale;
}

// ---------------- fused pv + bij update ----------------
// P[flat][slot][k] = sum_b prim2T[flat][b]*v2[cls][b][k] (LDS); then
// bij[m] += sum_{c,k} W*P + Wb.sv for the 80 m of this block's 8 locs
__global__ __launch_bounds__(256) void pv_bij_kernel(
    const float* __restrict__ prim2T, const float* __restrict__ v2,
    const float* __restrict__ W, const float* __restrict__ Wb,
    const float* __restrict__ sv, float* __restrict__ bij) {
  __shared__ float ps[64 * 260];      // [flat_l][b] padded
  __shared__ float vs[2 * 16 * 260];  // [cl][k][b] padded
  __shared__ float Ps[64][32];        // [flat_l][slot*16+k]
  int blk = blockIdx.x, tid = threadIdx.x;
  int loc0 = blk * 8;
  int I = (loc0 * 10) / 1152;
  for (int t = tid; t < 4096; t += 256) {
    int row = t >> 6, seg = t & 63;
    float4 a = *(const float4*)(prim2T + (size_t)(loc0 * 8 + row) * 256 + seg * 4);
    *(float4*)&ps[row * 260 + seg * 4] = a;
  }
  for (int cl = 0; cl < 2; ++cl) {
    int cls = I + cl;
    for (int t = tid; t < 4096; t += 256) {
      int b = t >> 4, k = t & 15;
      float val = (cls <= 9) ? v2[(size_t)cls * 4096 + t] : 0.f;
      vs[(cl * 16 + k) * 260 + b] = val;
    }
  }
  __syncthreads();
  {
    int k = tid & 15, fs = tid >> 4;
    const float4* ps4 = (const float4*)ps;
    const float4* vs4 = (const float4*)vs;
#pragma unroll
    for (int q = 0; q < 8; ++q) {
      int flat_l = fs * 4 + (q & 3);
      int slot = q >> 2;
      int loc = loc0 + (flat_l >> 3);
      int cls = (loc * 10) / 1152 + slot;
      int cl_idx = cls - I;
      if (cl_idx <= 1 && cls <= 9) {
        float a = 0.f;
        int bp = flat_l * 65, bv = (cl_idx * 16 + k) * 65;
        for (int b4 = 0; b4 < 64; ++b4) {
          float4 p4 = ps4[bp + b4];
          float4 w4 = vs4[bv + b4];
          a += p4.x * w4.x + p4.y * w4.y + p4.z * w4.z + p4.w * w4.w;
        }
        Ps[flat_l][slot * 16 + k] = a;
      }
    }
  }
  __syncthreads();
  if (tid < 80) {
    int ll = tid / 10, io = tid % 10;
    int loc = loc0 + ll;
    int m = loc * 10 + io;
    int i = m / 1152;
    int slot = i - (loc * 10) / 1152;
    const float* wrow = W + (size_t)io * 147456 + (size_t)loc * 128;
    float s = 0.f;
#pragma unroll
    for (int k = 0; k < 16; ++k) {
      float4 w0 = *(const float4*)(wrow + k * 8);
      float4 w1 = *(const float4*)(wrow + k * 8 + 4);
      s += w0.x * Ps[ll * 8 + 0][slot * 16 + k] + w0.y * Ps[ll * 8 + 1][slot * 16 + k]
         + w0.z * Ps[ll * 8 + 2][slot * 16 + k] + w0.w * Ps[ll * 8 + 3][slot * 16 + k];
      s += w1.x * Ps[ll * 8 + 4][slot * 16 + k] + w1.y * Ps[ll * 8 + 5][slot * 16 + k]
         + w1.z * Ps[ll * 8 + 6][slot * 16 + k] + w1.w * Ps[ll * 8 + 7][slot * 16 + k];
    }
    const float* wbr = Wb + (size_t)io * 18432 + (size_t)loc * 16;
    const float* svr = sv + i * 16;
#pragma unroll
    for (int k = 0; k < 16; ++k) s += wbr[k] * svr[k];
    bij[m] += s;
  }
}

extern "C" void kernel_launch(void* const* d_in, const int* in_sizes, int n_in,
                              void* d_out, int out_size, void* d_ws, size_t ws_size,
                              hipStream_t stream) {
  const float* x  = (const float*)d_in[0];
  const float* w1 = (const float*)d_in[1];
  const float* b1 = (const float*)d_in[2];
  const float* w2 = (const float*)d_in[3];
  const float* b2 = (const float*)d_in[4];
  const float* W  = (const float*)d_in[5];
  const float* Wb = (const float*)d_in[6];
  float* out = (float*)d_out;

  // workspace layout (~140 MB)
  u16*   hT     = (u16*)d_ws;                    // 26,214,400 u16
  u16*   w2bT   = hT + 26214400;                 //  5,308,416 u16
  float* pp     = (float*)(w2bT + 5308416);      //  7*2,359,296 f
  float* prim2T = pp + 7 * 2359296;              //  2,359,296 f
  float* vp     = prim2T + 2359296;              //    327,680 f
  float* v2     = vp + 327680;                   //     40,960 f
  float* cbuf   = v2 + 40960;                    //     11,520 f
  float* bij    = cbuf + 11520;                  //     11,520 f
  float* cb     = bij + 11520;                   //        160 f
  float* sv     = cb + 160;                      //        160 f

  hipMemsetAsync(bij, 0, 11520 * sizeof(float), stream);

  conv1_kernel<<<256, 256, 0, stream>>>(x, w1, b1, hT);
  w2b_kernel<<<256, 256, 0, stream>>>(w2, w2bT);
  conv2_mfma_kernel<<<dim3(36, 7), 512, 0, stream>>>(hT, w2bT, pp);
  prim_reduce_kernel<<<2304, 256, 0, stream>>>(pp, b2, prim2T);

  for (int r = 0; r < 3; ++r) {
    softmax_cb_kernel<<<10, 256, 0, stream>>>(bij, Wb, cbuf, cb);
    cwvgemm_kernel<<<dim3(8, 10), 256, 0, stream>>>(cbuf, W, prim2T, vp);
    squash_combine_kernel<<<10, 256, 0, stream>>>(vp, cb, v2, sv, out, r == 2 ? 1 : 0);
    if (r < 2) {
      pv_bij_kernel<<<144, 256, 0, stream>>>(prim2T, v2, W, Wb, sv, bij);
    }
  }
}